// Round 6
// baseline (267.585 us; speedup 1.0000x reference)
//
#include <hip/hip_runtime.h>

#define Bsz 4
#define Cin 64
#define C2c 128
#define Hh 256
#define Ww 256
#define Tt 16
#define HW (Hh*Ww)
#define PLANE (Bsz*4*HW)

typedef __attribute__((ext_vector_type(8))) short bf16x8;
typedef __attribute__((ext_vector_type(4))) float f32x4;

// ws layout (bytes)
#define XT_OFF  0
#define WBF_OFF 33554432
#define WTB_OFF 33701888
#define AUB_OFF 33718272
#define ZP_OFF  33727488

// prep index ranges
#define N_WTB 8192
#define N_WBF 73728
#define N_AUB 4608
#define N_ZP  64

__device__ __forceinline__ unsigned short f2bf(float f) {
  union { float f; unsigned u; } cv; cv.f = f;
  unsigned u = cv.u;
  unsigned r = (u + 0x7fffu + ((u >> 16) & 1u)) >> 16;   // RNE
  return (unsigned short)r;
}

// packed RNE f32x2 -> bf16x2 (single VALU op)
__device__ __forceinline__ unsigned cvtpk(float a, float b) {
  unsigned r;
  asm("v_cvt_pk_bf16_f32 %0, %1, %2" : "=v"(r) : "v"(a), "v"(b));
  return r;
}

union U8 { uint2 u2[2]; uint4 u4; bf16x8 v; };

// async global->LDS, 16B per lane; LDS dest must be wave-linear (base + lane*16)
#define GLOAD16(g, l) __builtin_amdgcn_global_load_lds( \
    (const __attribute__((address_space(1))) unsigned int*)(g), \
    (__attribute__((address_space(3))) unsigned int*)(l), 16, 0, 0)

// ---------- merged: x transpose (z<4, LDS-coalesced) + weight prep (z==4) ----------
__global__ __launch_bounds__(256) void xtp_kernel(
    const float* __restrict__ x, const float* __restrict__ W_out,
    const float* __restrict__ masks, const float* __restrict__ Wc,
    const float* __restrict__ W_aue,
    unsigned short* __restrict__ xT, unsigned short* __restrict__ Wtb,
    unsigned short* __restrict__ Wbf, unsigned short* __restrict__ Aub,
    unsigned short* __restrict__ Zp) {
  __shared__ unsigned short xs[64 * 132];
  const int tid = threadIdx.x;

  if (blockIdx.z == 4) {                              // ---- prep plane ----
    int i = (blockIdx.y * 2 + blockIdx.x) * 256 + tid;
    if (i < N_WTB) {                                  // Wtb[to][c]
      int to = i >> 7, c = i & 127;
      int t = to >> 2, o = to & 3;
      Wtb[i] = f2bf(W_out[o * C2c + c] * masks[t * C2c + c]);
    } else if (i < N_WTB + N_WBF) {                   // Wbf frag-ordered
      int idx = i - N_WTB;
      int j = idx & 7;
      int lane = (idx >> 3) & 63;
      int nt = (idx >> 9) & 7;
      int c = idx >> 12;
      int qq = lane >> 4;
      int tap = c >> 1;
      int ic = (c & 1) * 32 + qq * 8 + j;
      int n = nt * 16 + (lane & 15);
      Wbf[idx] = f2bf(Wc[((size_t)n * Cin + ic) * 9 + tap]);
    } else if (i < N_WTB + N_WBF + N_AUB) {           // Aub[4][1152]
      int idx = i - N_WTB - N_WBF;
      int m = idx / 1152, k = idx % 1152;
      int tap = k >> 7, c = k & 127;
      Aub[idx] = f2bf(W_aue[((size_t)m * C2c + c) * 9 + tap]);
    } else if (i < N_WTB + N_WBF + N_AUB + N_ZP) {    // zero page
      Zp[i - N_WTB - N_WBF - N_AUB] = 0;
    }
    return;
  }

  // ---- transpose plane: [bi][ic][y][x] f32 -> [bi][y][x][ic] bf16, 128-px tiles ----
  const int x0 = blockIdx.x * 128, y = blockIdx.y, bi = blockIdx.z;
  #pragma unroll
  for (int i = 0; i < 8; ++i) {
    int idx = i * 256 + tid;                          // 2048 float4s = 64 ic x 32
    int ic = idx >> 5, xq = idx & 31;
    float4 v = *(const float4*)(x + (((size_t)bi * Cin + ic) * Hh + y) * Ww + x0 + xq * 4);
    *(uint2*)(&xs[ic * 132 + xq * 4]) = make_uint2(cvtpk(v.x, v.y), cvtpk(v.z, v.w));
  }
  __syncthreads();
  #pragma unroll
  for (int j = 0; j < 4; ++j) {
    int idx = j * 256 + tid;                          // 1024 uint4s = 128 px x 8 icg
    int px = idx >> 3, icg = idx & 7;
    unsigned short u[8];
    #pragma unroll
    for (int k = 0; k < 8; ++k) u[k] = xs[(icg * 8 + k) * 132 + px];
    *(uint4*)(xT + (((size_t)bi * Hh + y) * Ww + (x0 + px)) * Cin + icg * 8) = *(uint4*)u;
  }
}

// ---------- fused: conv1 (haloed, MFMA) -> h in LDS -> GEMV + AU + stats ----------
// R6: 512-thread blocks (8 waves), same 16x8 tile. Per-wave state HALVED:
// acc[3][4]=48 AGPR (was 96), phase-2 one row/wave. Total ~118 regs/wave ->
// 4 waves/SIMD by unified-file math (R0-R5 were stuck at 2: 84 VGPR + 96 AGPR = 180).
// Wave wv: ph=wv>>1 (px quarter: 48 px), oh=wv&1 (oc half: 64 oc).
// x-view: two ic-halves, 256 records x 64B, slot XOR key (r>>1)&3.
// h-view: 180 records x 256B, 16x16B slots, key px&15. All LDS paths at bank floor.
__global__ __launch_bounds__(512, 4) void fused_kernel(
    const unsigned short* __restrict__ xT, const unsigned short* __restrict__ Wbf,
    const unsigned short* __restrict__ Wtb, const unsigned short* __restrict__ Aub,
    const unsigned short* __restrict__ Zp,
    const float* __restrict__ bc, const float* __restrict__ b_out,
    const float* __restrict__ b_aue, const float* __restrict__ lms,
    float* __restrict__ out) {
  __shared__ __align__(16) unsigned short sh[23040];   // 46080 B
  const int tid = threadIdx.x;
  const int x0 = blockIdx.x * 16, y0 = blockIdx.y * 8, bi = blockIdx.z;

  // ---- stage x-patch async: 2 ic-halves x 2 iters of 16B/lane, LDS-linear ----
  #pragma unroll
  for (int hf = 0; hf < 2; ++hf) {
    #pragma unroll
    for (int i = 0; i < 2; ++i) {
      int g = i * 512 + tid;                 // 1024 slots per half
      int r = g >> 2;                        // record 0..255 (240..255 dummy)
      int l = (g & 3) ^ ((r >> 1) & 3);      // logical ic-slot at this phys slot
      int pr = r / 20, pc = r - pr * 20;
      int gy = y0 - 2 + pr, gx = x0 - 2 + pc;
      bool ok = (r < 240) && ((unsigned)gy < Hh) && ((unsigned)gx < Ww);
      const unsigned short* src = ok
        ? xT + (((size_t)bi * Hh + gy) * Ww + gx) * Cin + (hf * 4 + l) * 8
        : Zp;
      GLOAD16(src, &sh[hf * 8192 + g * 8]);
    }
  }

  const int lane = tid & 63, wv = tid >> 6;            // wv 0..7
  const int n16 = lane & 15, q = lane >> 4;
  const int ph = wv >> 1, oh = wv & 1;

  int rbase[3];
  #pragma unroll
  for (int s = 0; s < 3; ++s) {
    int px = ph * 48 + s * 16 + n16;                  // 0..191 (>=180 garbage-safe)
    int pr = px / 18, pc = px % 18;
    rbase[s] = pr * 20 + pc;
  }

  f32x4 acc[3][4];
  #pragma unroll
  for (int s = 0; s < 3; ++s)
    #pragma unroll
    for (int mt = 0; mt < 4; ++mt) acc[s][mt] = (f32x4){0.f, 0.f, 0.f, 0.f};

  // ---- half 0 ready (first 2 per-lane loads), half 1 still in flight ----
  asm volatile("s_waitcnt vmcnt(2)" ::: "memory");
  __builtin_amdgcn_s_barrier();
  __builtin_amdgcn_sched_barrier(0);

  #pragma unroll
  for (int hf = 0; hf < 2; ++hf) {
    if (hf == 1) {
      asm volatile("s_waitcnt vmcnt(0)" ::: "memory");
      __builtin_amdgcn_s_barrier();
      __builtin_amdgcn_sched_barrier(0);
    }
    #pragma unroll
    for (int tap = 0; tap < 9; ++tap) {
      const int dd = (tap / 3) * 20 + (tap % 3);
      const int c = tap * 2 + hf;
      // this wave's 4 weight frags (oc-tiles oh*4 .. oh*4+3)
      bf16x8 wfr[4];
      const unsigned short* wb = Wbf + ((size_t)(c * 8 + oh * 4) * 64 + lane) * 8;
      #pragma unroll
      for (int mt = 0; mt < 4; ++mt)
        wfr[mt] = ((const U8*)(wb + mt * 512))->v;
      __builtin_amdgcn_s_setprio(1);
      #pragma unroll
      for (int s = 0; s < 3; ++s) {
        int rr = rbase[s] + dd;
        int a = hf * 8192 + rr * 32 + ((q ^ ((rr >> 1) & 3)) << 3);
        U8 t; t.u4 = *(const uint4*)(&sh[a]);          // ds_read_b128
        #pragma unroll
        for (int mt = 0; mt < 4; ++mt)
          acc[s][mt] =
            __builtin_amdgcn_mfma_f32_16x16x32_bf16(wfr[mt], t.v, acc[s][mt], 0, 0, 0);
      }
      __builtin_amdgcn_s_setprio(0);
    }
  }

  // ---- pack acc -> bf16 pairs (bias folded, border zeroed); acc dies here ----
  uint2 hp[3][4];
  #pragma unroll
  for (int s = 0; s < 3; ++s) {
    const int px = ph * 48 + s * 16 + n16;
    const int pr = px / 18, pc = px % 18;
    const int gy = y0 - 1 + pr, gx = x0 - 1 + pc;
    const bool valid = ((unsigned)gy < Hh) && ((unsigned)gx < Ww);
    #pragma unroll
    for (int mt = 0; mt < 4; ++mt) {
      const int ocl = oh * 64 + mt * 16 + q * 4;
      const float4 b4 = *(const float4*)(bc + ocl);
      unsigned lo = cvtpk(acc[s][mt][0] + b4.x, acc[s][mt][1] + b4.y);
      unsigned hi = cvtpk(acc[s][mt][2] + b4.z, acc[s][mt][3] + b4.w);
      hp[s][mt] = valid ? make_uint2(lo, hi) : make_uint2(0u, 0u);
    }
  }

  __syncthreads();                                     // x-view dead; reuse as h-view

  // ---- write h-patch (records 0..179, 256B), slot-swizzled, from packed regs ----
  #pragma unroll
  for (int s = 0; s < 3; ++s) {
    const int px = ph * 48 + s * 16 + n16;
    if (px < 180) {
      const int key = px & 15;
      #pragma unroll
      for (int mt = 0; mt < 4; ++mt) {
        const int ocl = oh * 64 + mt * 16 + q * 4;
        int a = px * 128 + (((ocl >> 3) ^ key) << 3) + (q & 1) * 4;
        *(uint2*)(&sh[a]) = hp[s][mt];
      }
    }
  }
  __syncthreads();

  // ---- phase 2: GEMV + AU from swizzled h-view; one output row per wave ----
  f32x4 accG[4];
  f32x4 accA = (f32x4){0.f, 0.f, 0.f, 0.f};
  #pragma unroll
  for (int mt = 0; mt < 4; ++mt) accG[mt] = (f32x4){0.f, 0.f, 0.f, 0.f};

  #pragma unroll
  for (int kc = 0; kc < 4; ++kc) {
    bf16x8 afr[4];
    #pragma unroll
    for (int mt = 0; mt < 4; ++mt)
      afr[mt] = ((const U8*)(Wtb + (size_t)(mt * 16 + n16) * C2c + kc * 32 + q * 8))->v;
    int hr = (wv + 1) * 18 + n16 + 1;
    int a = hr * 128 + (((kc * 4 + q) ^ (hr & 15)) << 3);
    U8 b; b.u4 = *(const uint4*)(&sh[a]);
    #pragma unroll
    for (int mt = 0; mt < 4; ++mt)
      accG[mt] = __builtin_amdgcn_mfma_f32_16x16x32_bf16(afr[mt], b.v, accG[mt], 0, 0, 0);
  }

  #pragma unroll
  for (int kc = 0; kc < 36; ++kc) {
    const int tap = kc >> 2, co4 = kc & 3;
    const int dy = tap / 3, dx = tap % 3;
    // A rows 4..15 feed D rows never read -> lanes n16>=4 may load garbage (row n16&3)
    bf16x8 afr = ((const U8*)(Aub + (size_t)(n16 & 3) * 1152 + kc * 32 + q * 8))->v;
    int hr = (wv + dy) * 18 + n16 + dx;
    int a = hr * 128 + (((co4 * 4 + q) ^ (hr & 15)) << 3);
    U8 b; b.u4 = *(const uint4*)(&sh[a]);
    accA = __builtin_amdgcn_mfma_f32_16x16x32_bf16(afr, b.v, accA, 0, 0, 0);
  }

  // ---- stats: lane holds to = mt*16 + q*4 + r -> t=4mt+q, o=r; row y0+wv ----
  const float b0 = b_out[0], b1 = b_out[1], b2 = b_out[2], b3 = b_out[3];
  const float ba = b_aue[q];
  const int px = x0 + n16;
  const int y = y0 + wv;
  float th[4][4];
  #pragma unroll
  for (int mt = 0; mt < 4; ++mt) {
    #pragma unroll
    for (int r = 0; r < 4; ++r) {
      float bo = (r == 0) ? b0 : (r == 1) ? b1 : (r == 2) ? b2 : b3;
      float v = accG[mt][r] + bo;
      float e = __expf(2.f * v);
      th[mt][r] = 1.f - 2.f / (e + 1.f);               // tanh(v)
    }
  }
  float mean_r[4], eu_r[4];
  #pragma unroll
  for (int r = 0; r < 4; ++r) {
    float s = th[0][r] + th[1][r] + th[2][r] + th[3][r];
    s += __shfl_xor(s, 16);
    s += __shfl_xor(s, 32);
    float m = s * (1.f / 16.f);
    float d0 = th[0][r] - m, d1 = th[1][r] - m, d2 = th[2][r] - m, d3 = th[3][r] - m;
    float vs = d0 * d0 + d1 * d1 + d2 * d2 + d3 * d3;
    vs += __shfl_xor(vs, 16);
    vs += __shfl_xor(vs, 32);
    mean_r[r] = m;
    eu_r[r] = vs * (1.f / 15.f);                       // ddof=1
  }
  float au_r[4];
  #pragma unroll
  for (int r = 0; r < 4; ++r) au_r[r] = __shfl(accA[r], n16);

  float m_q  = (q == 0) ? mean_r[0] : (q == 1) ? mean_r[1] : (q == 2) ? mean_r[2] : mean_r[3];
  float eu_q = (q == 0) ? eu_r[0]   : (q == 1) ? eu_r[1]   : (q == 2) ? eu_r[2]   : eu_r[3];
  float au_q = (q == 0) ? au_r[0]   : (q == 1) ? au_r[1]   : (q == 2) ? au_r[2]   : au_r[3];
  au_q = 1.f / (1.f + __expf(-(au_q + ba)));
  size_t oidx = ((size_t)(bi * 4 + q)) * HW + (size_t)y * Ww + px;
  float lm = lms[oidx];
  out[oidx] = au_q;
  out[PLANE + oidx] = eu_q;
  out[2 * (size_t)PLANE + oidx] = m_q + lm;
}

extern "C" void kernel_launch(void* const* d_in, const int* in_sizes, int n_in,
                              void* d_out, int out_size, void* d_ws, size_t ws_size,
                              hipStream_t stream) {
  const float* x      = (const float*)d_in[0];
  const float* lms    = (const float*)d_in[1];
  const float* W_conv = (const float*)d_in[2];
  const float* b_conv = (const float*)d_in[3];
  const float* W_out  = (const float*)d_in[4];
  const float* b_out  = (const float*)d_in[5];
  const float* W_aue  = (const float*)d_in[6];
  const float* b_aue  = (const float*)d_in[7];
  const float* masks  = (const float*)d_in[8];
  float* out = (float*)d_out;

  char* ws = (char*)d_ws;
  unsigned short* xT  = (unsigned short*)(ws + XT_OFF);
  unsigned short* Wbf = (unsigned short*)(ws + WBF_OFF);
  unsigned short* Wtb = (unsigned short*)(ws + WTB_OFF);
  unsigned short* Aub = (unsigned short*)(ws + AUB_OFF);
  unsigned short* Zp  = (unsigned short*)(ws + ZP_OFF);

  xtp_kernel<<<dim3(2, 256, 5), dim3(256), 0, stream>>>(x, W_out, masks, W_conv, W_aue,
                                                        xT, Wtb, Wbf, Aub, Zp);
  fused_kernel<<<dim3(16, 32, 4), dim3(512), 0, stream>>>(xT, Wbf, Wtb, Aub, Zp, b_conv,
                                                          b_out, b_aue, lms, out);
}

// Round 7
// 214.113 us; speedup vs baseline: 1.2497x; 1.2497x over previous
//
#include <hip/hip_runtime.h>

#define Bsz 4
#define Cin 64
#define C2c 128
#define Hh 256
#define Ww 256
#define Tt 16
#define HW (Hh*Ww)
#define PLANE (Bsz*4*HW)

typedef __attribute__((ext_vector_type(8))) short bf16x8;
typedef __attribute__((ext_vector_type(4))) float f32x4;

// ws layout (bytes)
#define XT_OFF  0
#define WBF_OFF 33554432
#define WTB_OFF 33701888
#define AUB_OFF 33718272
#define ZP_OFF  33727488

// prep index ranges
#define N_WTB 8192
#define N_WBF 73728
#define N_AUB 4608
#define N_ZP  64

__device__ __forceinline__ unsigned short f2bf(float f) {
  union { float f; unsigned u; } cv; cv.f = f;
  unsigned u = cv.u;
  unsigned r = (u + 0x7fffu + ((u >> 16) & 1u)) >> 16;   // RNE
  return (unsigned short)r;
}

// packed RNE f32x2 -> bf16x2 (single VALU op)
__device__ __forceinline__ unsigned cvtpk(float a, float b) {
  unsigned r;
  asm("v_cvt_pk_bf16_f32 %0, %1, %2" : "=v"(r) : "v"(a), "v"(b));
  return r;
}

union U8 { uint2 u2[2]; uint4 u4; bf16x8 v; };

// async global->LDS, 16B per lane; LDS dest must be wave-linear (base + lane*16)
#define GLOAD16(g, l) __builtin_amdgcn_global_load_lds( \
    (const __attribute__((address_space(1))) unsigned int*)(g), \
    (__attribute__((address_space(3))) unsigned int*)(l), 16, 0, 0)

// ---------- merged: x transpose (z<4, LDS-coalesced) + weight prep (z==4) ----------
__global__ __launch_bounds__(256) void xtp_kernel(
    const float* __restrict__ x, const float* __restrict__ W_out,
    const float* __restrict__ masks, const float* __restrict__ Wc,
    const float* __restrict__ W_aue,
    unsigned short* __restrict__ xT, unsigned short* __restrict__ Wtb,
    unsigned short* __restrict__ Wbf, unsigned short* __restrict__ Aub,
    unsigned short* __restrict__ Zp) {
  __shared__ unsigned short xs[64 * 132];
  const int tid = threadIdx.x;

  if (blockIdx.z == 4) {                              // ---- prep plane ----
    int i = (blockIdx.y * 2 + blockIdx.x) * 256 + tid;
    if (i < N_WTB) {                                  // Wtb[to][c]
      int to = i >> 7, c = i & 127;
      int t = to >> 2, o = to & 3;
      Wtb[i] = f2bf(W_out[o * C2c + c] * masks[t * C2c + c]);
    } else if (i < N_WTB + N_WBF) {                   // Wbf frag-ordered
      int idx = i - N_WTB;
      int j = idx & 7;
      int lane = (idx >> 3) & 63;
      int nt = (idx >> 9) & 7;
      int c = idx >> 12;
      int qq = lane >> 4;
      int tap = c >> 1;
      int ic = (c & 1) * 32 + qq * 8 + j;
      int n = nt * 16 + (lane & 15);
      Wbf[idx] = f2bf(Wc[((size_t)n * Cin + ic) * 9 + tap]);
    } else if (i < N_WTB + N_WBF + N_AUB) {           // Aub[4][1152]
      int idx = i - N_WTB - N_WBF;
      int m = idx / 1152, k = idx % 1152;
      int tap = k >> 7, c = k & 127;
      Aub[idx] = f2bf(W_aue[((size_t)m * C2c + c) * 9 + tap]);
    } else if (i < N_WTB + N_WBF + N_AUB + N_ZP) {    // zero page
      Zp[i - N_WTB - N_WBF - N_AUB] = 0;
    }
    return;
  }

  // ---- transpose plane: [bi][ic][y][x] f32 -> [bi][y][x][ic] bf16, 128-px tiles ----
  const int x0 = blockIdx.x * 128, y = blockIdx.y, bi = blockIdx.z;
  #pragma unroll
  for (int i = 0; i < 8; ++i) {
    int idx = i * 256 + tid;                          // 2048 float4s = 64 ic x 32
    int ic = idx >> 5, xq = idx & 31;
    float4 v = *(const float4*)(x + (((size_t)bi * Cin + ic) * Hh + y) * Ww + x0 + xq * 4);
    *(uint2*)(&xs[ic * 132 + xq * 4]) = make_uint2(cvtpk(v.x, v.y), cvtpk(v.z, v.w));
  }
  __syncthreads();
  #pragma unroll
  for (int j = 0; j < 4; ++j) {
    int idx = j * 256 + tid;                          // 1024 uint4s = 128 px x 8 icg
    int px = idx >> 3, icg = idx & 7;
    unsigned short u[8];
    #pragma unroll
    for (int k = 0; k < 8; ++k) u[k] = xs[(icg * 8 + k) * 132 + px];
    *(uint4*)(xT + (((size_t)bi * Hh + y) * Ww + (x0 + px)) * Cin + icg * 8) = *(uint4*)u;
  }
}

// ---------- fused: conv1 (haloed, MFMA) -> h in LDS -> GEMV + AU + stats ----------
// R7 = R2 (best measured, 108us) + ONE change: LDS-staged double-buffered weights.
// Per chunk: stage chunk k+1 (8KB) via 2x global_load_lds -> ds_read wfr from
// buf[k&1] (linear b128, conflict-free) -> 24 MFMA -> vmcnt(0)+barrier.
// Weight L2 latency hides under compute; 72 per-wave global loads eliminated.
// LDS: x-view 32KB [0,16384) + wbuf 2x4096 shorts [16384,24576); h-view 46KB
// overlays [0,23040) after phase-1 barrier. Total 49152 B -> still 3 blocks/CU.
__global__ __launch_bounds__(256, 3) void fused_kernel(
    const unsigned short* __restrict__ xT, const unsigned short* __restrict__ Wbf,
    const unsigned short* __restrict__ Wtb, const unsigned short* __restrict__ Aub,
    const unsigned short* __restrict__ Zp,
    const float* __restrict__ bc, const float* __restrict__ b_out,
    const float* __restrict__ b_aue, const float* __restrict__ lms,
    float* __restrict__ out) {
  __shared__ __align__(16) unsigned short sh[24576];   // 49152 B
  const int tid = threadIdx.x;
  const int x0 = blockIdx.x * 16, y0 = blockIdx.y * 8, bi = blockIdx.z;

  // ---- stage x-patch async: 2 ic-halves x 4 iters of 16B/lane, LDS-linear ----
  #pragma unroll
  for (int hf = 0; hf < 2; ++hf) {
    #pragma unroll
    for (int i = 0; i < 4; ++i) {
      int g = i * 256 + tid;                 // 1024 slots per half
      int r = g >> 2;                        // record 0..255 (240..255 dummy)
      int l = (g & 3) ^ ((r >> 1) & 3);      // logical ic-slot at this phys slot
      int pr = r / 20, pc = r - pr * 20;
      int gy = y0 - 2 + pr, gx = x0 - 2 + pc;
      bool ok = (r < 240) && ((unsigned)gy < Hh) && ((unsigned)gx < Ww);
      const unsigned short* src = ok
        ? xT + (((size_t)bi * Hh + gy) * Ww + gx) * Cin + (hf * 4 + l) * 8
        : Zp;
      GLOAD16(src, &sh[hf * 8192 + g * 8]);
    }
  }
  // ---- stage weights for first chunk (c=0) into wbuf 0 ----
  {
    const unsigned short* wsrc = Wbf;                  // chunk 0
    GLOAD16(wsrc + tid * 8, &sh[16384 + tid * 8]);
    GLOAD16(wsrc + (256 + tid) * 8, &sh[16384 + (256 + tid) * 8]);
  }

  const int lane = tid & 63, wv = tid >> 6;
  const int n16 = lane & 15, q = lane >> 4;
  const int ph = wv >> 1, oh = wv & 1;

  int rbase[6];
  #pragma unroll
  for (int s = 0; s < 6; ++s) {
    int px = ph * 96 + s * 16 + n16;                  // 0..191 (>=180 garbage-safe)
    int pr = px / 18, pc = px % 18;
    rbase[s] = pr * 20 + pc;
  }

  f32x4 acc[6][4];
  #pragma unroll
  for (int s = 0; s < 6; ++s)
    #pragma unroll
    for (int mt = 0; mt < 4; ++mt) acc[s][mt] = (f32x4){0.f, 0.f, 0.f, 0.f};

  // ---- single full drain: x both halves + w chunk 0 ----
  asm volatile("s_waitcnt vmcnt(0)" ::: "memory");
  __builtin_amdgcn_s_barrier();
  __builtin_amdgcn_sched_barrier(0);

  // ---- K-loop: 18 chunks, seq k; chunk(k) = (k<9) ? 2k (hf=0) : 2(k-9)+1 (hf=1) ----
  #pragma unroll
  for (int k = 0; k < 18; ++k) {
    const int hf = (k < 9) ? 0 : 1;
    const int tap = (k < 9) ? k : k - 9;
    const int dd = (tap / 3) * 20 + (tap % 3);

    // prefetch next chunk's weights into the other buffer (async DMA)
    if (k < 17) {
      const int kn = k + 1;
      const int cn = (kn < 9) ? 2 * kn : 2 * (kn - 9) + 1;
      const unsigned short* wsrc = Wbf + (size_t)cn * 4096;
      unsigned short* wdst = (unsigned short*)&sh[16384 + (kn & 1) * 4096];
      GLOAD16(wsrc + tid * 8, wdst + tid * 8);
      GLOAD16(wsrc + (256 + tid) * 8, wdst + (256 + tid) * 8);
    }

    // this wave's 4 weight frags from LDS (linear b128, conflict-free)
    const int wb_s = 16384 + (k & 1) * 4096;
    bf16x8 wfr[4];
    #pragma unroll
    for (int mt = 0; mt < 4; ++mt)
      wfr[mt] = ((const U8*)(&sh[wb_s + ((oh * 4 + mt) * 64 + lane) * 8]))->v;

    __builtin_amdgcn_s_setprio(1);
    #pragma unroll
    for (int s = 0; s < 6; ++s) {
      int rr = rbase[s] + dd;
      int a = hf * 8192 + rr * 32 + ((q ^ ((rr >> 1) & 3)) << 3);
      U8 t; t.u4 = *(const uint4*)(&sh[a]);            // ds_read_b128
      #pragma unroll
      for (int mt = 0; mt < 4; ++mt)
        acc[s][mt] =
          __builtin_amdgcn_mfma_f32_16x16x32_bf16(wfr[mt], t.v, acc[s][mt], 0, 0, 0);
    }
    __builtin_amdgcn_s_setprio(0);

    // next-chunk weights landed + everyone done reading buf[(k+1)&1]'s old contents
    if (k < 17) {
      asm volatile("s_waitcnt vmcnt(0)" ::: "memory");
      __builtin_amdgcn_s_barrier();
    }
  }
  __syncthreads();                                     // x-view + wbuf dead; h-view

  // ---- write h-patch (records 0..179, 256B), packed cvt, slot-swizzled ----
  #pragma unroll
  for (int s = 0; s < 6; ++s) {
    const int px = ph * 96 + s * 16 + n16;
    if (px < 180) {
      const int pr = px / 18, pc = px % 18;
      const int gy = y0 - 1 + pr, gx = x0 - 1 + pc;
      const bool valid = ((unsigned)gy < Hh) && ((unsigned)gx < Ww);
      const int key = px & 15;
      #pragma unroll
      for (int mt = 0; mt < 4; ++mt) {
        const int ocl = oh * 64 + mt * 16 + q * 4;
        const float4 b4 = *(const float4*)(bc + ocl);
        unsigned lo = cvtpk(acc[s][mt][0] + b4.x, acc[s][mt][1] + b4.y);
        unsigned hi = cvtpk(acc[s][mt][2] + b4.z, acc[s][mt][3] + b4.w);
        if (!valid) { lo = 0u; hi = 0u; }              // zero-pad h outside image
        int a = px * 128 + (((ocl >> 3) ^ key) << 3) + (q & 1) * 4;
        *(uint2*)(&sh[a]) = make_uint2(lo, hi);
      }
    }
  }
  __syncthreads();

  // ---- phase 2: GEMV + AU from swizzled h-view (all reads b128) ----
  f32x4 accG[2][4];
  f32x4 accA[2];
  #pragma unroll
  for (int nt = 0; nt < 2; ++nt) {
    accA[nt] = (f32x4){0.f, 0.f, 0.f, 0.f};
    #pragma unroll
    for (int mt = 0; mt < 4; ++mt) accG[nt][mt] = (f32x4){0.f, 0.f, 0.f, 0.f};
  }

  #pragma unroll
  for (int kc = 0; kc < 4; ++kc) {
    bf16x8 afr[4];
    #pragma unroll
    for (int mt = 0; mt < 4; ++mt)
      afr[mt] = ((const U8*)(Wtb + (size_t)(mt * 16 + n16) * C2c + kc * 32 + q * 8))->v;
    #pragma unroll
    for (int nt = 0; nt < 2; ++nt) {
      int hr = (wv * 2 + nt + 1) * 18 + n16 + 1;
      int a = hr * 128 + (((kc * 4 + q) ^ (hr & 15)) << 3);
      U8 b; b.u4 = *(const uint4*)(&sh[a]);
      #pragma unroll
      for (int mt = 0; mt < 4; ++mt)
        accG[nt][mt] = __builtin_amdgcn_mfma_f32_16x16x32_bf16(afr[mt], b.v, accG[nt][mt], 0, 0, 0);
    }
  }

  #pragma unroll
  for (int kc = 0; kc < 36; ++kc) {
    const int tap = kc >> 2, co4 = kc & 3;
    const int dy = tap / 3, dx = tap % 3;
    // A rows 4..15 feed D rows never read -> lanes n16>=4 may load garbage (row n16&3)
    bf16x8 afr = ((const U8*)(Aub + (size_t)(n16 & 3) * 1152 + kc * 32 + q * 8))->v;
    #pragma unroll
    for (int nt = 0; nt < 2; ++nt) {
      int hr = (wv * 2 + nt + dy) * 18 + n16 + dx;
      int a = hr * 128 + (((co4 * 4 + q) ^ (hr & 15)) << 3);
      U8 b; b.u4 = *(const uint4*)(&sh[a]);
      accA[nt] = __builtin_amdgcn_mfma_f32_16x16x32_bf16(afr, b.v, accA[nt], 0, 0, 0);
    }
  }

  // ---- stats: lane holds to = mt*16 + q*4 + r -> t=4mt+q, o=r ----
  const float b0 = b_out[0], b1 = b_out[1], b2 = b_out[2], b3 = b_out[3];
  const float ba = b_aue[q];
  const int px = x0 + n16;
  #pragma unroll
  for (int nt = 0; nt < 2; ++nt) {
    const int y = y0 + wv * 2 + nt;
    float th[4][4];
    #pragma unroll
    for (int mt = 0; mt < 4; ++mt) {
      #pragma unroll
      for (int r = 0; r < 4; ++r) {
        float bo = (r == 0) ? b0 : (r == 1) ? b1 : (r == 2) ? b2 : b3;
        float v = accG[nt][mt][r] + bo;
        float e = __expf(2.f * v);
        th[mt][r] = 1.f - 2.f / (e + 1.f);             // tanh(v)
      }
    }
    float mean_r[4], eu_r[4];
    #pragma unroll
    for (int r = 0; r < 4; ++r) {
      float s = th[0][r] + th[1][r] + th[2][r] + th[3][r];
      s += __shfl_xor(s, 16);
      s += __shfl_xor(s, 32);
      float m = s * (1.f / 16.f);
      float d0 = th[0][r] - m, d1 = th[1][r] - m, d2 = th[2][r] - m, d3 = th[3][r] - m;
      float vs = d0 * d0 + d1 * d1 + d2 * d2 + d3 * d3;
      vs += __shfl_xor(vs, 16);
      vs += __shfl_xor(vs, 32);
      mean_r[r] = m;
      eu_r[r] = vs * (1.f / 15.f);                     // ddof=1
    }
    float au_r[4];
    #pragma unroll
    for (int r = 0; r < 4; ++r) au_r[r] = __shfl(accA[nt][r], n16);

    float m_q  = (q == 0) ? mean_r[0] : (q == 1) ? mean_r[1] : (q == 2) ? mean_r[2] : mean_r[3];
    float eu_q = (q == 0) ? eu_r[0]   : (q == 1) ? eu_r[1]   : (q == 2) ? eu_r[2]   : eu_r[3];
    float au_q = (q == 0) ? au_r[0]   : (q == 1) ? au_r[1]   : (q == 2) ? au_r[2]   : au_r[3];
    au_q = 1.f / (1.f + __expf(-(au_q + ba)));
    size_t oidx = ((size_t)(bi * 4 + q)) * HW + (size_t)y * Ww + px;
    float lm = lms[oidx];
    out[oidx] = au_q;
    out[PLANE + oidx] = eu_q;
    out[2 * (size_t)PLANE + oidx] = m_q + lm;
  }
}

extern "C" void kernel_launch(void* const* d_in, const int* in_sizes, int n_in,
                              void* d_out, int out_size, void* d_ws, size_t ws_size,
                              hipStream_t stream) {
  const float* x      = (const float*)d_in[0];
  const float* lms    = (const float*)d_in[1];
  const float* W_conv = (const float*)d_in[2];
  const float* b_conv = (const float*)d_in[3];
  const float* W_out  = (const float*)d_in[4];
  const float* b_out  = (const float*)d_in[5];
  const float* W_aue  = (const float*)d_in[6];
  const float* b_aue  = (const float*)d_in[7];
  const float* masks  = (const float*)d_in[8];
  float* out = (float*)d_out;

  char* ws = (char*)d_ws;
  unsigned short* xT  = (unsigned short*)(ws + XT_OFF);
  unsigned short* Wbf = (unsigned short*)(ws + WBF_OFF);
  unsigned short* Wtb = (unsigned short*)(ws + WTB_OFF);
  unsigned short* Aub = (unsigned short*)(ws + AUB_OFF);
  unsigned short* Zp  = (unsigned short*)(ws + ZP_OFF);

  xtp_kernel<<<dim3(2, 256, 5), dim3(256), 0, stream>>>(x, W_out, masks, W_conv, W_aue,
                                                        xT, Wtb, Wbf, Aub, Zp);
  fused_kernel<<<dim3(16, 32, 4), dim3(256), 0, stream>>>(xT, Wbf, Wtb, Aub, Zp, b_conv,
                                                          b_out, b_aue, lms, out);
}